// Round 1
// baseline (358.676 us; speedup 1.0000x reference)
//
#include <hip/hip_runtime.h>
#include <math.h>

#define NE 128
#define NU 64
#define NA 32
#define NSV 512
#define NPV 64

// ---------------------------------------------------------------------------
// K1: geometry. One block per electron e (128 blocks x 128 threads).
// Writes sv0 (128x128), p0 (128x128x4), expsum (128).
// ---------------------------------------------------------------------------
__global__ __launch_bounds__(128)
void geom_kernel(const float* __restrict__ r, const float* __restrict__ apos,
                 float* __restrict__ sv0, float* __restrict__ p0,
                 float* __restrict__ expsum)
{
    int e = blockIdx.x;
    int t = threadIdx.x;
    float rx = r[e*3+0], ry = r[e*3+1], rz = r[e*3+2];

    // pair features: p0[e][j][c] = r[j]-r[e], len (0 on diag)
    {
        int j = t;
        float dx = r[j*3+0]-rx, dy = r[j*3+1]-ry, dz = r[j*3+2]-rz;
        float len = sqrtf(dx*dx + dy*dy + dz*dz);
        if (j == e) len = 0.f;
        float* pp = p0 + (e*NE + j)*4;
        pp[0]=dx; pp[1]=dy; pp[2]=dz; pp[3]=len;
    }
    // single features + expsum
    float ex = 0.f;
    if (t < NA) {
        float dx = rx - apos[t*3+0], dy = ry - apos[t*3+1], dz = rz - apos[t*3+2];
        float len = sqrtf(dx*dx + dy*dy + dz*dz);
        float* sp = sv0 + e*128 + t*4;
        sp[0]=dx; sp[1]=dy; sp[2]=dz; sp[3]=len;
        ex = expf(-len);
    }
    if (t < 64) {   // wave 0 reduction (lanes 32..63 contribute 0)
        #pragma unroll
        for (int off = 32; off; off >>= 1) ex += __shfl_down(ex, off);
        if (t == 0) expsum[e] = ex;
    }
}

// ---------------------------------------------------------------------------
// K2..K5: fused layer kernel.
// Blocks [0,128): s-stream GEMM  svOut = tanh(s_in @ Vw + Vb)
//   s_in[e] = [su_mean | sd_mean | pmu[e] | pmd[e] | sv[e]]  (means computed
//   redundantly per block; mean-segments folded into per-column t1 once).
// Blocks [128,640): pair-stream update pOut = tanh(pIn @ Ww + Wb) (+pIn if RES)
// FS = input s width, FP = input p width. Output widths fixed: 512 / 64.
// ---------------------------------------------------------------------------
template<int FS, int FP, bool RES>
__global__ __launch_bounds__(256)
void layer_kernel(const float* __restrict__ svIn, const float* __restrict__ pIn,
                  const float* __restrict__ Vw, const float* __restrict__ Vb,
                  const float* __restrict__ Ww, const float* __restrict__ Wb,
                  float* __restrict__ svOut, float* __restrict__ pOut)
{
    constexpr int ASH = 2*FS + 32*FP + 16*FS + 256 + 32;
    constexpr int BSH = 32*FP + FP*64;
    constexpr int SH  = (ASH > BSH) ? ASH : BSH;
    __shared__ __align__(16) float sh[SH];
    const int t = threadIdx.x;

    if (blockIdx.x < 128) {
        // ---------------- A role: s-stream GEMM, tile 16e x 32o ----------------
        float* meanS = sh;                 // 2*FS
        float* pm    = meanS + 2*FS;       // 16 * 2*FP
        float* svT   = pm + 32*FP;         // 16*FS
        float* red   = svT + 16*FS;        // 256
        float* t1s   = red + 256;          // 32
        const int bA = blockIdx.x;
        const int e0 = (bA >> 4) * 16;
        const int o0 = (bA & 15) * 32;

        // s means (over spin-up rows / spin-down rows)
        for (int f = t; f < 2*FS; f += 256) {
            int col = (f < FS) ? f : f - FS;
            int i0  = (f < FS) ? 0 : 64;
            const float* base = svIn + i0*FS + col;
            float s0=0,s1=0,s2=0,s3=0;
            for (int i = 0; i < 64; i += 4) {
                s0 += base[(i+0)*FS]; s1 += base[(i+1)*FS];
                s2 += base[(i+2)*FS]; s3 += base[(i+3)*FS];
            }
            meanS[f] = (s0+s1+s2+s3) * 0.015625f;
        }
        // p means for this block's 16 electrons: pm[e_l][c], c<FP = up-mean, c>=FP = down-mean
        for (int idx = t; idx < 32*FP; idx += 256) {
            int c   = idx % (2*FP);
            int e_l = idx / (2*FP);
            int i0  = (c < FP) ? 0 : 64;
            int cc  = (c < FP) ? c : c - FP;
            const float* base = pIn + (size_t)(i0*NE + e0 + e_l)*FP + cc;
            float s0=0,s1=0,s2=0,s3=0;
            for (int i = 0; i < 64; i += 4) {
                s0 += base[(size_t)(i+0)*NE*FP]; s1 += base[(size_t)(i+1)*NE*FP];
                s2 += base[(size_t)(i+2)*NE*FP]; s3 += base[(size_t)(i+3)*NE*FP];
            }
            pm[e_l*2*FP + c] = (s0+s1+s2+s3) * 0.015625f;
        }
        // stage sv tile
        for (int idx = t; idx < 16*FS; idx += 256)
            svT[idx] = svIn[(e0 + idx/FS)*FS + (idx % FS)];
        __syncthreads();

        // t1[o] = Vb[o] + su_mean . Vw[0:FS] + sd_mean . Vw[FS:2FS]  (electron-independent)
        {
            int g = t >> 5, ol = t & 31, o = o0 + ol;
            float part = 0.f;
            for (int f = g; f < 2*FS; f += 8)
                part += meanS[f] * Vw[f*NSV + o];
            red[g*32 + ol] = part;
        }
        __syncthreads();
        if (t < 32) {
            float s = Vb[o0 + t];
            #pragma unroll
            for (int g = 0; g < 8; ++g) s += red[g*32 + t];
            t1s[t] = s;
        }
        __syncthreads();

        // main: each thread -> 2 outputs (e0+ty, e0+ty+8) x (o0+ol)
        {
            const int ol = t & 31, ty = t >> 5;
            const int o = o0 + ol;
            float acc0 = t1s[ol], acc1 = t1s[ol];
            const float* Wp  = Vw + (size_t)(2*FS)*NSV + o;
            const float* pmA = pm + ty*2*FP;
            const float* pmB = pm + (ty+8)*2*FP;
            #pragma unroll 4
            for (int c = 0; c < 2*FP; ++c) {
                float w = Wp[(size_t)c*NSV];
                acc0 = fmaf(pmA[c], w, acc0);
                acc1 = fmaf(pmB[c], w, acc1);
            }
            const float* Ws  = Vw + (size_t)(2*FS + 2*FP)*NSV + o;
            const float* a0p = svT + ty*FS;
            const float* a1p = svT + (ty+8)*FS;
            for (int f = 0; f < FS; f += 4) {
                float4 a0 = *reinterpret_cast<const float4*>(a0p + f);
                float4 a1 = *reinterpret_cast<const float4*>(a1p + f);
                float w0 = Ws[(size_t)(f+0)*NSV], w1 = Ws[(size_t)(f+1)*NSV];
                float w2 = Ws[(size_t)(f+2)*NSV], w3 = Ws[(size_t)(f+3)*NSV];
                acc0 = fmaf(a0.x,w0,acc0); acc0 = fmaf(a0.y,w1,acc0);
                acc0 = fmaf(a0.z,w2,acc0); acc0 = fmaf(a0.w,w3,acc0);
                acc1 = fmaf(a1.x,w0,acc1); acc1 = fmaf(a1.y,w1,acc1);
                acc1 = fmaf(a1.z,w2,acc1); acc1 = fmaf(a1.w,w3,acc1);
            }
            svOut[(e0+ty)*NSV + o]   = tanhf(acc0);
            svOut[(e0+ty+8)*NSV + o] = tanhf(acc1);
        }
    } else {
        // ---------------- B role: pair update, 32 pairs/block ----------------
        float* inT = sh;              // 32*FP
        float* Wl  = inT + 32*FP;     // FP*64
        const int bb = blockIdx.x - 128;
        const int pair0 = bb * 32;
        for (int idx = t; idx < 32*FP; idx += 256)
            inT[idx] = pIn[(size_t)pair0*FP + idx];
        for (int idx = t; idx < FP*64; idx += 256)
            Wl[idx] = Ww[idx];
        __syncthreads();
        const int pl = t >> 3;       // pair slot 0..31
        const int oc = t & 7;        // 8 outputs each
        const int o0 = oc * 8;
        float acc[8];
        #pragma unroll
        for (int k = 0; k < 8; ++k) acc[k] = Wb[o0 + k];
        const float* a = inT + pl*FP;
        #pragma unroll 4
        for (int c = 0; c < FP; ++c) {
            float av = a[c];
            const float* wr = Wl + c*64 + o0;
            float4 wA = *reinterpret_cast<const float4*>(wr);
            float4 wB = *reinterpret_cast<const float4*>(wr + 4);
            acc[0]=fmaf(av,wA.x,acc[0]); acc[1]=fmaf(av,wA.y,acc[1]);
            acc[2]=fmaf(av,wA.z,acc[2]); acc[3]=fmaf(av,wA.w,acc[3]);
            acc[4]=fmaf(av,wB.x,acc[4]); acc[5]=fmaf(av,wB.y,acc[5]);
            acc[6]=fmaf(av,wB.z,acc[6]); acc[7]=fmaf(av,wB.w,acc[7]);
        }
        float* outp = pOut + (size_t)(pair0 + pl)*64 + o0;
        #pragma unroll
        for (int k = 0; k < 8; ++k) {
            float v = tanhf(acc[k]);
            if (RES) v += a[o0 + k];
            outp[k] = v;
        }
    }
}

// ---------------------------------------------------------------------------
// K6: heads. su = sv[:64]@vhu_w + b, sd = sv[64:]@vhd_w + b.  128 blocks.
// ---------------------------------------------------------------------------
__global__ __launch_bounds__(256)
void heads_kernel(const float* __restrict__ svF,
                  const float* __restrict__ vhu_w, const float* __restrict__ vhu_b,
                  const float* __restrict__ vhd_w, const float* __restrict__ vhd_b,
                  float* __restrict__ sout)
{
    __shared__ __align__(16) float row[512];
    const int b = blockIdx.x;
    const int spin = b >> 6, el = b & 63;
    const int e = spin*64 + el;
    const int t = threadIdx.x;
    row[t]     = svF[e*NSV + t];
    row[t+256] = svF[e*NSV + t + 256];
    __syncthreads();
    const float* W = spin ? vhd_w : vhu_w;
    const float* B = spin ? vhd_b : vhu_b;
    float acc = B[t];
    for (int f = 0; f < 512; f += 4) {
        float4 a = *reinterpret_cast<const float4*>(&row[f]);
        acc = fmaf(a.x, W[(size_t)(f+0)*256 + t], acc);
        acc = fmaf(a.y, W[(size_t)(f+1)*256 + t], acc);
        acc = fmaf(a.z, W[(size_t)(f+2)*256 + t], acc);
        acc = fmaf(a.w, W[(size_t)(f+3)*256 + t], acc);
    }
    sout[(size_t)(spin*64 + el)*256 + t] = acc;
}

// ---------------------------------------------------------------------------
// K7: orbital matrices. orb[spin][i][o] = (s[i]@W[:,o] + b[o]) * expsum. 32 blocks.
// ---------------------------------------------------------------------------
__global__ __launch_bounds__(256)
void sw_kernel(const float* __restrict__ s,
               const float* __restrict__ wu_w, const float* __restrict__ wu_b,
               const float* __restrict__ wd_w, const float* __restrict__ wd_b,
               const float* __restrict__ expsum,
               float* __restrict__ orb)
{
    const int b = blockIdx.x;           // 32 blocks: spin = b>>4, 4 rows each
    const int spin = b >> 4;
    const int t = threadIdx.x;
    const int il = t >> 6, o = t & 63;
    const int i = (b & 15)*4 + il;
    const float* W = spin ? wd_w : wu_w;
    const float* B = spin ? wd_b : wu_b;
    const float* srow = s + (size_t)(spin*64 + i)*256;
    float acc = B[o];
    #pragma unroll 4
    for (int k = 0; k < 256; ++k)
        acc = fmaf(srow[k], W[(size_t)k*64 + o], acc);
    orb[(size_t)(spin*64 + i)*64 + o] = acc * expsum[spin*64 + i];
}

// ---------------------------------------------------------------------------
// K8: two 64x64 log|det| via partial-pivot LU, one wave per matrix.
// Rows live in registers (fully unrolled), pivot-row broadcast via __shfl.
// out[0] = ld_u + ld_d  (== log|psi|: psi collapses to sign*exp(0)).
// ---------------------------------------------------------------------------
__global__ __launch_bounds__(128)
void det_kernel(const float* __restrict__ orb, float* __restrict__ out)
{
    __shared__ float parts[2];
    const int t = threadIdx.x;
    const int w = t >> 6;
    const int lane = t & 63;
    const float* M = orb + (size_t)w*4096 + (size_t)lane*64;
    float rr[64];
    #pragma unroll
    for (int j = 0; j < 64; j += 4) {
        float4 v = *reinterpret_cast<const float4*>(M + j);
        rr[j]=v.x; rr[j+1]=v.y; rr[j+2]=v.z; rr[j+3]=v.w;
    }
    float ld = 0.f;
    bool active = true;
    #pragma unroll
    for (int k = 0; k < 64; ++k) {
        float v = active ? fabsf(rr[k]) : -1.f;
        int idx = lane;
        #pragma unroll
        for (int off = 32; off; off >>= 1) {
            float ov = __shfl_xor(v, off);
            int   oi = __shfl_xor(idx, off);
            if (ov > v || (ov == v && oi < idx)) { v = ov; idx = oi; }
        }
        float piv = __shfl(rr[k], idx);
        ld += logf(v);
        float linv = 1.f / piv;
        float l = (active && lane != idx) ? rr[k]*linv : 0.f;
        if (lane == idx) active = false;
        #pragma unroll
        for (int j = k+1; j < 64; ++j)
            rr[j] = fmaf(-l, __shfl(rr[j], idx), rr[j]);
    }
    if (lane == 0) parts[w] = ld;
    __syncthreads();
    if (t == 0) out[0] = parts[0] + parts[1];
}

// ---------------------------------------------------------------------------
extern "C" void kernel_launch(void* const* d_in, const int* in_sizes, int n_in,
                              void* d_out, int out_size, void* d_ws, size_t ws_size,
                              hipStream_t stream)
{
    const float* r    = (const float*)d_in[0];
    const float* apos = (const float*)d_in[1];
    const float* V0w  = (const float*)d_in[2];
    const float* V0b  = (const float*)d_in[3];
    const float* W0w  = (const float*)d_in[4];
    const float* W0b  = (const float*)d_in[5];
    const float* V1w  = (const float*)d_in[6];
    const float* V1b  = (const float*)d_in[7];
    const float* W1w  = (const float*)d_in[8];
    const float* W1b  = (const float*)d_in[9];
    const float* V2w  = (const float*)d_in[10];
    const float* V2b  = (const float*)d_in[11];
    const float* W2w  = (const float*)d_in[12];
    const float* W2b  = (const float*)d_in[13];
    const float* afw  = (const float*)d_in[14];
    const float* afb  = (const float*)d_in[15];
    const float* vhuw = (const float*)d_in[16];
    const float* vhub = (const float*)d_in[17];
    const float* vhdw = (const float*)d_in[18];
    const float* vhdb = (const float*)d_in[19];
    const float* wuw  = (const float*)d_in[20];
    const float* wub  = (const float*)d_in[21];
    const float* wdw  = (const float*)d_in[22];
    const float* wdb  = (const float*)d_in[23];

    float* ws   = (float*)d_ws;
    float* sv0  = ws;                    // 128*128
    float* p0   = sv0 + 128*128;         // 128*128*4
    float* pA   = p0  + 128*128*4;       // 128*128*64
    float* pB   = pA  + 128*128*64;      // 128*128*64
    float* svA  = pB  + 128*128*64;      // 128*512
    float* svB  = svA + 128*512;         // 128*512
    float* expv = svB + 128*512;         // 128
    float* sdu  = expv + 128;            // 128*256
    float* orb  = sdu + 128*256;         // 2*64*64

    geom_kernel<<<128, 128, 0, stream>>>(r, apos, sv0, p0, expv);
    layer_kernel<128, 4, false><<<640, 256, 0, stream>>>(sv0, p0, V0w, V0b, W0w, W0b, svA, pA);
    layer_kernel<512, 64, true><<<640, 256, 0, stream>>>(svA, pA, V1w, V1b, W1w, W1b, svB, pB);
    layer_kernel<512, 64, true><<<640, 256, 0, stream>>>(svB, pB, V2w, V2b, W2w, W2b, svA, pA);
    // after-layer: GEMM role only (grid 128); p outputs untouched
    layer_kernel<512, 64, true><<<128, 256, 0, stream>>>(svA, pA, afw, afb, W2w, W2b, svB, pA);
    heads_kernel<<<128, 256, 0, stream>>>(svB, vhuw, vhub, vhdw, vhdb, sdu);
    sw_kernel<<<32, 256, 0, stream>>>(sdu, wuw, wub, wdw, wdb, expv, orb);
    det_kernel<<<1, 128, 0, stream>>>(orb, (float*)d_out);
}

// Round 2
// 201.540 us; speedup vs baseline: 1.7797x; 1.7797x over previous
//
#include <hip/hip_runtime.h>
#include <math.h>

#define NE 128
#define NA 32
#define NSV 512

// ---------------------------------------------------------------------------
// K1: geometry. One block per electron e (128 blocks x 128 threads).
// Writes sv0 (128x128), p0 (128x128x4), expsum (128).
// ---------------------------------------------------------------------------
__global__ __launch_bounds__(128)
void geom_kernel(const float* __restrict__ r, const float* __restrict__ apos,
                 float* __restrict__ sv0, float* __restrict__ p0,
                 float* __restrict__ expsum)
{
    int e = blockIdx.x;
    int t = threadIdx.x;
    float rx = r[e*3+0], ry = r[e*3+1], rz = r[e*3+2];

    {   // pair features p0[e][j][c] = r[j]-r[e], len (0 on diag)
        int j = t;
        float dx = r[j*3+0]-rx, dy = r[j*3+1]-ry, dz = r[j*3+2]-rz;
        float len = sqrtf(dx*dx + dy*dy + dz*dz);
        if (j == e) len = 0.f;
        float* pp = p0 + (e*NE + j)*4;
        pp[0]=dx; pp[1]=dy; pp[2]=dz; pp[3]=len;
    }
    float ex = 0.f;
    if (t < NA) {
        float dx = rx - apos[t*3+0], dy = ry - apos[t*3+1], dz = rz - apos[t*3+2];
        float len = sqrtf(dx*dx + dy*dy + dz*dz);
        float* sp = sv0 + e*128 + t*4;
        sp[0]=dx; sp[1]=dy; sp[2]=dz; sp[3]=len;
        ex = expf(-len);
    }
    if (t < 64) {
        #pragma unroll
        for (int off = 32; off; off >>= 1) ex += __shfl_down(ex, off);
        if (t == 0) expsum[e] = ex;
    }
}

// ---------------------------------------------------------------------------
// MB kernel: fused {p-means, s-means, pair-update}.
//  blocks [0,PB): pmean   — coalesced column sums of pIn (contiguous per row)
//  blocks [PB,PB+SB): smean
//  blocks [PB+SB, ...): B role  pOut = tanh(pIn@Ww + Wb) (+pIn if RES)
// ---------------------------------------------------------------------------
template<int FS, int FP, bool RES>
__global__ __launch_bounds__(256)
void mb_kernel(const float* __restrict__ svIn, const float* __restrict__ pIn,
               const float* __restrict__ Ww, const float* __restrict__ Wb,
               float* __restrict__ smean, float* __restrict__ pme,
               float* __restrict__ pOut)
{
    constexpr int PB   = (128*FP)/256;
    constexpr int SB   = (2*FS)/256;
    constexpr int PADP = FP + 4;
    __shared__ __align__(16) float sh[32*PADP + FP*64];
    const int t = threadIdx.x;
    const int b = blockIdx.x;

    if (b < PB) {
        // pmean: tg = j*FP + c; for fixed i the whole grid reads contiguously
        const int tg = b*256 + t;
        const float* base = pIn + tg;
        float aU = 0.f, aD = 0.f;
        #pragma unroll 4
        for (int i = 0; i < 64; ++i) {
            aU += base[(size_t)i*(128*FP)];
            aD += base[(size_t)(i+64)*(128*FP)];
        }
        const int j = tg / FP, c = tg % FP;
        pme[j*(2*FP) + c]      = aU * 0.015625f;
        pme[j*(2*FP) + FP + c] = aD * 0.015625f;
    } else if (b < PB + SB) {
        const int f   = (b-PB)*256 + t;           // < 2*FS
        const int col = (f < FS) ? f : f - FS;
        const int i0  = (f < FS) ? 0 : 64;
        const float* base = svIn + (size_t)i0*FS + col;
        float s = 0.f;
        #pragma unroll 4
        for (int i = 0; i < 64; ++i) s += base[(size_t)i*FS];
        smean[f] = s * 0.015625f;
    } else {
        // ---------------- B role: pair update, 32 pairs/block ----------------
        float* inT = sh;                  // 32 * PADP
        float* Wl  = sh + 32*PADP;        // FP * 64
        const int pair0 = (b - PB - SB) * 32;
        for (int idx = t; idx < 32*FP; idx += 256)
            inT[(idx/FP)*PADP + (idx%FP)] = pIn[(size_t)pair0*FP + idx];
        for (int idx = t; idx < FP*64; idx += 256)
            Wl[idx] = Ww[idx];
        __syncthreads();
        const int pl = t >> 3, oc = t & 7, o0 = oc*8;
        float acc[8];
        #pragma unroll
        for (int k = 0; k < 8; ++k) acc[k] = Wb[o0 + k];
        const float* a = inT + pl*PADP;
        #pragma unroll 4
        for (int c = 0; c < FP; ++c) {
            float av = a[c];
            const float* wr = Wl + c*64 + o0;
            float4 wA = *reinterpret_cast<const float4*>(wr);
            float4 wB = *reinterpret_cast<const float4*>(wr + 4);
            acc[0]=fmaf(av,wA.x,acc[0]); acc[1]=fmaf(av,wA.y,acc[1]);
            acc[2]=fmaf(av,wA.z,acc[2]); acc[3]=fmaf(av,wA.w,acc[3]);
            acc[4]=fmaf(av,wB.x,acc[4]); acc[5]=fmaf(av,wB.y,acc[5]);
            acc[6]=fmaf(av,wB.z,acc[6]); acc[7]=fmaf(av,wB.w,acc[7]);
        }
        float* outp = pOut + (size_t)(pair0 + pl)*64 + o0;
        #pragma unroll
        for (int k = 0; k < 8; ++k) {
            float v = tanhf(acc[k]);
            if (RES) v += a[o0 + k];
            outp[k] = v;
        }
    }
}

// ---------------------------------------------------------------------------
// A kernel: s-stream GEMM. out[e][o] = tanh(t1[o] + A'[e] . W'[:,o])
//   A'[e] = [pme[e] (2FP) | sv[e] (FS)], W' = Vw rows [2FS, 2FS+KP)
//   t1[o] = Vb[o] + smean . Vw[0:2FS]  (computed in-block, K-split 8 ways)
// Grid: 256 blocks = 32 e-tiles(4) x 8 o-tiles(64). 512 threads = 8 waves:
//   main loop K-split across wave halves (kh = wv>>2), e_l = wv&3.
// ---------------------------------------------------------------------------
template<int FS, int FP>
__global__ __launch_bounds__(512)
void a_kernel(const float* __restrict__ svIn, const float* __restrict__ pme,
              const float* __restrict__ smean,
              const float* __restrict__ Vw, const float* __restrict__ Vb,
              float* __restrict__ svOut)
{
    constexpr int KP  = 2*FP + FS;
    constexpr int KP2 = KP/2;
    constexpr int T1I = (2*FS)/8;
    __shared__ __align__(16) float smeanL[2*FS];
    __shared__ __align__(16) float As[4*KP];
    __shared__ __align__(16) float red[512];
    __shared__ float t1s[64];
    const int t  = threadIdx.x;
    const int eg = (blockIdx.x >> 3) * 4;
    const int o0 = (blockIdx.x & 7) * 64;
    const int ol = t & 63;
    const int o  = o0 + ol;
    const int wv = t >> 6;

    for (int idx = t; idx < 2*FS; idx += 512) smeanL[idx] = smean[idx];
    for (int idx = t; idx < 4*(2*FP); idx += 512)
        As[(idx/(2*FP))*KP + (idx%(2*FP))] = pme[(eg + idx/(2*FP))*(2*FP) + (idx%(2*FP))];
    for (int idx = t; idx < 4*FS; idx += 512)
        As[(idx/FS)*KP + 2*FP + (idx%FS)] = svIn[(size_t)(eg + idx/FS)*FS + (idx%FS)];
    __syncthreads();

    // t1 partials: K = 2*FS split over 8 waves
    {
        float acc = 0.f;
        const float* Wp = Vw + (size_t)(wv*T1I)*NSV + o;
        const float* sm = smeanL + wv*T1I;
        #pragma unroll 8
        for (int i = 0; i < T1I; ++i)
            acc = fmaf(sm[i], Wp[(size_t)i*NSV], acc);
        red[wv*64 + ol] = acc;
    }
    __syncthreads();
    if (t < 64) {
        float s = Vb[o0 + t];
        #pragma unroll
        for (int g = 0; g < 8; ++g) s += red[g*64 + t];
        t1s[t] = s;
    }
    __syncthreads();

    // main: per-e K-split halves
    {
        const int e_l = wv & 3, kh = wv >> 2;
        float acc = (kh == 0) ? t1s[ol] : 0.f;
        const float* Ap = As + e_l*KP + kh*KP2;          // wave-uniform base
        const float* Wp = Vw + (size_t)(2*FS + kh*KP2)*NSV + o;
        #pragma unroll 8
        for (int i = 0; i < KP2; ++i)
            acc = fmaf(Ap[i], Wp[(size_t)i*NSV], acc);
        red[wv*64 + ol] = acc;
    }
    __syncthreads();
    if (t < 256) {
        const int e_l = t >> 6, oo = t & 63;
        float s = red[e_l*64 + oo] + red[(e_l+4)*64 + oo];
        svOut[(size_t)(eg + e_l)*NSV + o0 + oo] = tanhf(s);
    }
}

// ---------------------------------------------------------------------------
// heads+sw fused: per electron, tmp = sv@vh + b (256), orb_row = (tmp@w + b)*expsum
// 128 blocks x 512 threads.
// ---------------------------------------------------------------------------
__global__ __launch_bounds__(512)
void headsw_kernel(const float* __restrict__ svF,
                   const float* __restrict__ vhu_w, const float* __restrict__ vhu_b,
                   const float* __restrict__ vhd_w, const float* __restrict__ vhd_b,
                   const float* __restrict__ wu_w,  const float* __restrict__ wu_b,
                   const float* __restrict__ wd_w,  const float* __restrict__ wd_b,
                   const float* __restrict__ expv,  float* __restrict__ orb)
{
    __shared__ __align__(16) float row[512];
    __shared__ __align__(16) float redH[512];
    __shared__ __align__(16) float tmpL[256];
    const int e = blockIdx.x;
    const int spin = e >> 6;
    const int t = threadIdx.x;
    row[t] = svF[(size_t)e*NSV + t];
    __syncthreads();

    const float* W1 = spin ? vhd_w : vhu_w;
    const float* B1 = spin ? vhd_b : vhu_b;
    {
        const int o = t & 255, kc = t >> 8;       // kc in {0,1}
        float acc = kc ? 0.f : B1[o];
        const float* Wp = W1 + (size_t)(kc*256)*256 + o;
        const float* rp = row + kc*256;
        #pragma unroll 8
        for (int f = 0; f < 256; ++f)
            acc = fmaf(rp[f], Wp[(size_t)f*256], acc);
        redH[t] = acc;
    }
    __syncthreads();
    if (t < 256) tmpL[t] = redH[t] + redH[256 + t];
    __syncthreads();

    const float* W2 = spin ? wd_w : wu_w;
    const float* B2 = spin ? wd_b : wu_b;
    {
        const int o = t & 63, kc = t >> 6;        // kc in 0..7
        float acc = 0.f;
        const float* Wp = W2 + (size_t)(kc*32)*64 + o;
        const float* tp = tmpL + kc*32;
        #pragma unroll
        for (int f = 0; f < 32; ++f)
            acc = fmaf(tp[f], Wp[(size_t)f*64], acc);
        redH[kc*64 + o] = acc;
    }
    __syncthreads();
    if (t < 64) {
        float s = B2[t];
        #pragma unroll
        for (int g = 0; g < 8; ++g) s += redH[g*64 + t];
        orb[(size_t)e*64 + t] = s * expv[e];
    }
}

// ---------------------------------------------------------------------------
// det: two 64x64 log|det| via partial-pivot LU, one wave per matrix.
// out[0] = ld_u + ld_d.
// ---------------------------------------------------------------------------
__global__ __launch_bounds__(128)
void det_kernel(const float* __restrict__ orb, float* __restrict__ out)
{
    __shared__ float parts[2];
    const int t = threadIdx.x;
    const int w = t >> 6;
    const int lane = t & 63;
    const float* M = orb + (size_t)w*4096 + (size_t)lane*64;
    float rr[64];
    #pragma unroll
    for (int j = 0; j < 64; j += 4) {
        float4 v = *reinterpret_cast<const float4*>(M + j);
        rr[j]=v.x; rr[j+1]=v.y; rr[j+2]=v.z; rr[j+3]=v.w;
    }
    float ld = 0.f;
    bool active = true;
    #pragma unroll
    for (int k = 0; k < 64; ++k) {
        float v = active ? fabsf(rr[k]) : -1.f;
        int idx = lane;
        #pragma unroll
        for (int off = 32; off; off >>= 1) {
            float ov = __shfl_xor(v, off);
            int   oi = __shfl_xor(idx, off);
            if (ov > v || (ov == v && oi < idx)) { v = ov; idx = oi; }
        }
        float piv = __shfl(rr[k], idx);
        ld += logf(v);
        float linv = 1.f / piv;
        float l = (active && lane != idx) ? rr[k]*linv : 0.f;
        if (lane == idx) active = false;
        #pragma unroll
        for (int j = k+1; j < 64; ++j)
            rr[j] = fmaf(-l, __shfl(rr[j], idx), rr[j]);
    }
    if (lane == 0) parts[w] = ld;
    __syncthreads();
    if (t == 0) out[0] = parts[0] + parts[1];
}

// ---------------------------------------------------------------------------
extern "C" void kernel_launch(void* const* d_in, const int* in_sizes, int n_in,
                              void* d_out, int out_size, void* d_ws, size_t ws_size,
                              hipStream_t stream)
{
    const float* r    = (const float*)d_in[0];
    const float* apos = (const float*)d_in[1];
    const float* V0w  = (const float*)d_in[2];
    const float* V0b  = (const float*)d_in[3];
    const float* W0w  = (const float*)d_in[4];
    const float* W0b  = (const float*)d_in[5];
    const float* V1w  = (const float*)d_in[6];
    const float* V1b  = (const float*)d_in[7];
    const float* W1w  = (const float*)d_in[8];
    const float* W1b  = (const float*)d_in[9];
    const float* V2w  = (const float*)d_in[10];
    const float* V2b  = (const float*)d_in[11];
    const float* W2w  = (const float*)d_in[12];
    const float* W2b  = (const float*)d_in[13];
    const float* afw  = (const float*)d_in[14];
    const float* afb  = (const float*)d_in[15];
    const float* vhuw = (const float*)d_in[16];
    const float* vhub = (const float*)d_in[17];
    const float* vhdw = (const float*)d_in[18];
    const float* vhdb = (const float*)d_in[19];
    const float* wuw  = (const float*)d_in[20];
    const float* wub  = (const float*)d_in[21];
    const float* wdw  = (const float*)d_in[22];
    const float* wdb  = (const float*)d_in[23];

    float* ws    = (float*)d_ws;
    float* sv0   = ws;                    // 128*128
    float* p0    = sv0  + 128*128;        // 128*128*4
    float* pA    = p0   + 128*128*4;      // 128*128*64
    float* pB    = pA   + 128*128*64;     // 128*128*64
    float* svA   = pB   + 128*128*64;     // 128*512
    float* svB   = svA  + 128*512;        // 128*512
    float* expv  = svB  + 128*512;        // 128
    float* smean = expv + 128;            // 1024
    float* pme   = smean + 1024;          // 128*128
    float* orb   = pme  + 128*128;        // 2*64*64

    geom_kernel<<<128, 128, 0, stream>>>(r, apos, sv0, p0, expv);

    // layer 0: means(sv0,p0) + pair-update p0->pA, then s-GEMM sv0->svA
    mb_kernel<128, 4, false><<<515, 256, 0, stream>>>(sv0, p0, W0w, W0b, smean, pme, pA);
    a_kernel<128, 4><<<256, 512, 0, stream>>>(sv0, pme, smean, V0w, V0b, svA);

    // layer 1
    mb_kernel<512, 64, true><<<548, 256, 0, stream>>>(svA, pA, W1w, W1b, smean, pme, pB);
    a_kernel<512, 64><<<256, 512, 0, stream>>>(svA, pme, smean, V1w, V1b, svB);

    // layer 2
    mb_kernel<512, 64, true><<<548, 256, 0, stream>>>(svB, pB, W2w, W2b, smean, pme, pA);
    a_kernel<512, 64><<<256, 512, 0, stream>>>(svB, pme, smean, V2w, V2b, svA);

    // after-layer: means only (grid = PB+SB = 36), then s-GEMM with after_w
    mb_kernel<512, 64, true><<<36, 256, 0, stream>>>(svA, pA, W2w, W2b, smean, pme, pB);
    a_kernel<512, 64><<<256, 512, 0, stream>>>(svA, pme, smean, afw, afb, svB);

    headsw_kernel<<<128, 512, 0, stream>>>(svB, vhuw, vhub, vhdw, vhdb,
                                           wuw, wub, wdw, wdb, expv, orb);
    det_kernel<<<1, 128, 0, stream>>>(orb, (float*)d_out);
}

// Round 4
// 175.555 us; speedup vs baseline: 2.0431x; 1.1480x over previous
//
#include <hip/hip_runtime.h>
#include <math.h>

#define NE 128
#define NA 32
#define NSV 512

// ---------------------------------------------------------------------------
// K1: geometry. One block per electron e (128 blocks x 128 threads).
// Writes sv0 (128x128), p0 (128x128x4), expsum (128).
// ---------------------------------------------------------------------------
__global__ __launch_bounds__(128)
void geom_kernel(const float* __restrict__ r, const float* __restrict__ apos,
                 float* __restrict__ sv0, float* __restrict__ p0,
                 float* __restrict__ expsum)
{
    int e = blockIdx.x;
    int t = threadIdx.x;
    float rx = r[e*3+0], ry = r[e*3+1], rz = r[e*3+2];

    {   // pair features p0[e][j][c] = r[j]-r[e], len (0 on diag)
        int j = t;
        float dx = r[j*3+0]-rx, dy = r[j*3+1]-ry, dz = r[j*3+2]-rz;
        float len = sqrtf(dx*dx + dy*dy + dz*dz);
        if (j == e) len = 0.f;
        float* pp = p0 + (e*NE + j)*4;
        pp[0]=dx; pp[1]=dy; pp[2]=dz; pp[3]=len;
    }
    float ex = 0.f;
    if (t < NA) {
        float dx = rx - apos[t*3+0], dy = ry - apos[t*3+1], dz = rz - apos[t*3+2];
        float len = sqrtf(dx*dx + dy*dy + dz*dz);
        float* sp = sv0 + e*128 + t*4;
        sp[0]=dx; sp[1]=dy; sp[2]=dz; sp[3]=len;
        ex = expf(-len);
    }
    if (t < 64) {
        #pragma unroll
        for (int off = 32; off; off >>= 1) ex += __shfl_down(ex, off);
        if (t == 0) expsum[e] = ex;
    }
}

// ---------------------------------------------------------------------------
// MB kernel: fused {p-means, t1 projection, pair-update}.
//  blocks [0,PB): pmean — coalesced column sums of pIn
//  blocks [PB,PB+8): t1[o] = Vb[o] + smean . Vw[0:2FS]  (means computed in-block)
//  blocks [PB+8,...): B role  pOut = tanh(pIn@Ww + Wb) (+pIn if RES)
// ---------------------------------------------------------------------------
template<int FS, int FP, bool RES>
__global__ __launch_bounds__(256)
void mb_kernel(const float* __restrict__ svIn, const float* __restrict__ pIn,
               const float* __restrict__ Ww, const float* __restrict__ Wb,
               const float* __restrict__ Vw, const float* __restrict__ Vb,
               float* __restrict__ pme, float* __restrict__ t1g,
               float* __restrict__ pOut)
{
    constexpr int PB   = (128*FP)/256;
    constexpr int PADP = FP + 4;
    constexpr int SH1  = 32*PADP + FP*64;
    constexpr int SH2  = 2*FS + 256;
    constexpr int SH   = (SH1 > SH2) ? SH1 : SH2;
    __shared__ __align__(16) float sh[SH];
    const int t = threadIdx.x;
    const int b = blockIdx.x;

    if (b < PB) {
        // pmean: tg = j*FP + c; for fixed i the whole grid reads contiguously
        const int tg = b*256 + t;
        const float* base = pIn + tg;
        float aU = 0.f, aD = 0.f;
        #pragma unroll 4
        for (int i = 0; i < 64; ++i) {
            aU += base[(size_t)i*(128*FP)];
            aD += base[(size_t)(i+64)*(128*FP)];
        }
        const int j = tg / FP, c = tg % FP;
        pme[j*(2*FP) + c]      = aU * 0.015625f;
        pme[j*(2*FP) + FP + c] = aD * 0.015625f;
    } else if (b < PB + 8) {
        // ---------------- t1 role ----------------
        float* meanL = sh;              // 2*FS (unscaled col sums)
        float* redT  = sh + 2*FS;       // 256
        const int o0 = (b - PB) * 64;
        for (int c = t; c < 2*FS; c += 256) {
            const int col = (c < FS) ? c : c - FS;
            const int i0  = (c < FS) ? 0 : 64;
            const float* base = svIn + (size_t)i0*FS + col;
            float s = 0.f;
            #pragma unroll 8
            for (int i = 0; i < 64; ++i) s += base[(size_t)i*FS];
            meanL[c] = s;
        }
        __syncthreads();
        constexpr int KQ = (2*FS)/4;
        const int o = o0 + (t & 63), kq = t >> 6;
        float acc = 0.f;
        const float* Wp = Vw + (size_t)(kq*KQ)*NSV + o;
        const float* mp = meanL + kq*KQ;
        #pragma unroll 8
        for (int i = 0; i < KQ; ++i)
            acc = fmaf(mp[i], Wp[(size_t)i*NSV], acc);
        redT[t] = acc;
        __syncthreads();
        if (t < 64) {
            float s = redT[t] + redT[64+t] + redT[128+t] + redT[192+t];
            t1g[o0 + t] = fmaf(s, 0.015625f, Vb[o0 + t]);
        }
    } else {
        // ---------------- B role: pair update, 32 pairs/block ----------------
        float* inT = sh;                  // 32 * PADP
        float* Wl  = sh + 32*PADP;        // FP * 64
        const int pair0 = (b - PB - 8) * 32;
        for (int idx = t; idx < 32*FP; idx += 256)
            inT[(idx/FP)*PADP + (idx%FP)] = pIn[(size_t)pair0*FP + idx];
        for (int idx = t; idx < FP*64; idx += 256)
            Wl[idx] = Ww[idx];
        __syncthreads();
        const int pl = t >> 3, oc = t & 7, o0 = oc*8;
        float acc[8];
        #pragma unroll
        for (int k = 0; k < 8; ++k) acc[k] = Wb[o0 + k];
        const float* a = inT + pl*PADP;
        #pragma unroll 4
        for (int c = 0; c < FP; ++c) {
            float av = a[c];
            const float* wr = Wl + c*64 + o0;
            float4 wA = *reinterpret_cast<const float4*>(wr);
            float4 wB = *reinterpret_cast<const float4*>(wr + 4);
            acc[0]=fmaf(av,wA.x,acc[0]); acc[1]=fmaf(av,wA.y,acc[1]);
            acc[2]=fmaf(av,wA.z,acc[2]); acc[3]=fmaf(av,wA.w,acc[3]);
            acc[4]=fmaf(av,wB.x,acc[4]); acc[5]=fmaf(av,wB.y,acc[5]);
            acc[6]=fmaf(av,wB.z,acc[6]); acc[7]=fmaf(av,wB.w,acc[7]);
        }
        float* outp = pOut + (size_t)(pair0 + pl)*64 + o0;
        #pragma unroll
        for (int k = 0; k < 8; ++k) {
            float v = tanhf(acc[k]);
            if (RES) v += a[o0 + k];
            outp[k] = v;
        }
    }
}

// ---------------------------------------------------------------------------
// A kernel: s-stream GEMM. out[e][o] = tanh(t1g[o] + A'[e] . W'[:,o])
//   A'[e] = [pme[e] (2FP) | sv[e] (FS)], W' = Vw rows [2FS, 2FS+KP)
// Grid: 256 blocks = 32 e-tiles(4) x 8 o-tiles(64). 512 threads = 8 waves:
//   wv = kh*4 + e_l  (K halved across wave groups).
// ---------------------------------------------------------------------------
template<int FS, int FP>
__global__ __launch_bounds__(512)
void a_kernel(const float* __restrict__ svIn, const float* __restrict__ pme,
              const float* __restrict__ t1g, const float* __restrict__ Vw,
              float* __restrict__ svOut)
{
    constexpr int KP  = 2*FP + FS;
    constexpr int KP2 = KP/2;
    __shared__ __align__(16) float As[4*KP];
    __shared__ __align__(16) float red[512];
    const int t  = threadIdx.x;
    const int eg = (blockIdx.x >> 3) * 4;
    const int o0 = (blockIdx.x & 7) * 64;
    const int ol = t & 63;
    const int o  = o0 + ol;
    const int wv = t >> 6;

    for (int idx = t; idx < 4*(2*FP); idx += 512)
        As[(idx/(2*FP))*KP + (idx%(2*FP))] = pme[(eg + idx/(2*FP))*(2*FP) + (idx%(2*FP))];
    for (int idx = t; idx < 4*FS; idx += 512)
        As[(idx/FS)*KP + 2*FP + (idx%FS)] = svIn[(size_t)(eg + idx/FS)*FS + (idx%FS)];
    __syncthreads();

    {
        const int e_l = wv & 3, kh = wv >> 2;
        float acc = (kh == 0) ? t1g[o] : 0.f;
        const float* Ap = As + e_l*KP + kh*KP2;          // wave-uniform base
        const float* Wp = Vw + (size_t)(2*FS + kh*KP2)*NSV + o;
        #pragma unroll 16
        for (int i = 0; i < KP2; ++i)
            acc = fmaf(Ap[i], Wp[(size_t)i*NSV], acc);
        red[wv*64 + ol] = acc;
    }
    __syncthreads();
    if (t < 256) {
        const int e_l = t >> 6, oo = t & 63;
        float s = red[e_l*64 + oo] + red[(e_l+4)*64 + oo];
        svOut[(size_t)(eg + e_l)*NSV + o0 + oo] = tanhf(s);
    }
}

// ---------------------------------------------------------------------------
// heads+sw fused: per electron, tmp = sv@vh + b (256), orb_row = (tmp@w + b)*expsum
// 128 blocks x 512 threads.
// ---------------------------------------------------------------------------
__global__ __launch_bounds__(512)
void headsw_kernel(const float* __restrict__ svF,
                   const float* __restrict__ vhu_w, const float* __restrict__ vhu_b,
                   const float* __restrict__ vhd_w, const float* __restrict__ vhd_b,
                   const float* __restrict__ wu_w,  const float* __restrict__ wu_b,
                   const float* __restrict__ wd_w,  const float* __restrict__ wd_b,
                   const float* __restrict__ expv,  float* __restrict__ orb)
{
    __shared__ __align__(16) float row[512];
    __shared__ __align__(16) float redH[512];
    __shared__ __align__(16) float tmpL[256];
    const int e = blockIdx.x;
    const int spin = e >> 6;
    const int t = threadIdx.x;
    row[t] = svF[(size_t)e*NSV + t];
    __syncthreads();

    const float* W1 = spin ? vhd_w : vhu_w;
    const float* B1 = spin ? vhd_b : vhu_b;
    {
        const int o = t & 255, kc = t >> 8;       // kc in {0,1}
        float acc = kc ? 0.f : B1[o];
        const float* Wp = W1 + (size_t)(kc*256)*256 + o;
        const float* rp = row + kc*256;
        #pragma unroll 8
        for (int f = 0; f < 256; ++f)
            acc = fmaf(rp[f], Wp[(size_t)f*256], acc);
        redH[t] = acc;
    }
    __syncthreads();
    if (t < 256) tmpL[t] = redH[t] + redH[256 + t];
    __syncthreads();

    const float* W2 = spin ? wd_w : wu_w;
    const float* B2 = spin ? wd_b : wu_b;
    {
        const int o = t & 63, kc = t >> 6;        // kc in 0..7
        float acc = 0.f;
        const float* Wp = W2 + (size_t)(kc*32)*64 + o;
        const float* tp = tmpL + kc*32;
        #pragma unroll
        for (int f = 0; f < 32; ++f)
            acc = fmaf(tp[f], Wp[(size_t)f*64], acc);
        redH[kc*64 + o] = acc;
    }
    __syncthreads();
    if (t < 64) {
        float s = B2[t];
        #pragma unroll
        for (int g = 0; g < 8; ++g) s += redH[g*64 + t];
        orb[(size_t)e*64 + t] = s * expv[e];
    }
}

// ---------------------------------------------------------------------------
// det: two 64x64 log|det| via partial-pivot LU, one wave per matrix.
// DPP packed argmax (VALU-only), v_readlane row broadcasts (BIT-CAST — the
// builtin is int-typed; value-converting floats truncates and was R2's bug),
// logf of pivots deferred out of the chain. out[0] = ld_u + ld_d.
// ---------------------------------------------------------------------------
__device__ __forceinline__ int imax2(int a, int b) { return a > b ? a : b; }

__device__ __forceinline__ float readlane_f(float x, int lane) {
    return __int_as_float(__builtin_amdgcn_readlane(__float_as_int(x), lane));
}

__global__ __launch_bounds__(128)
void det_kernel(const float* __restrict__ orb, float* __restrict__ out)
{
    __shared__ float parts[2];
    const int t = threadIdx.x;
    const int w = t >> 6;
    const int lane = t & 63;
    const float* M = orb + (size_t)w*4096 + (size_t)lane*64;
    float rr[64];
    #pragma unroll
    for (int j = 0; j < 64; j += 4) {
        float4 v = *reinterpret_cast<const float4*>(M + j);
        rr[j]=v.x; rr[j+1]=v.y; rr[j+2]=v.z; rr[j+3]=v.w;
    }
    float pv_mine = 1.f;
    bool active = true;
    #pragma unroll
    for (int k = 0; k < 64; ++k) {
        // packed |value| (sign+low6 bits dropped) | lane; inactive lanes -> lane only
        int bits = (int)(__float_as_uint(rr[k]) & 0x7FFFFFC0u);
        int v = active ? (bits | lane) : lane;
        int tmp;
        tmp = __builtin_amdgcn_update_dpp(0, v, 0xB1,  0xF, 0xF, true); v = imax2(v, tmp); // quad xor1
        tmp = __builtin_amdgcn_update_dpp(0, v, 0x4E,  0xF, 0xF, true); v = imax2(v, tmp); // quad xor2
        tmp = __builtin_amdgcn_update_dpp(0, v, 0x141, 0xF, 0xF, true); v = imax2(v, tmp); // half mirror
        tmp = __builtin_amdgcn_update_dpp(0, v, 0x140, 0xF, 0xF, true); v = imax2(v, tmp); // row mirror
        tmp = __builtin_amdgcn_update_dpp(0, v, 0x142, 0xF, 0xF, true); v = imax2(v, tmp); // bcast15
        tmp = __builtin_amdgcn_update_dpp(0, v, 0x143, 0xF, 0xF, true); v = imax2(v, tmp); // bcast31
        const int idx = __builtin_amdgcn_readlane(v, 63) & 63;        // uniform (SGPR)
        const float piv = readlane_f(rr[k], idx);
        pv_mine = (lane == k) ? piv : pv_mine;                        // defer log
        const float linv = __builtin_amdgcn_rcpf(piv);
        const float l = (active && lane != idx) ? rr[k]*linv : 0.f;
        if (lane == idx) active = false;
        #pragma unroll
        for (int j = k+1; j < 64; ++j) {
            const float uj = readlane_f(rr[j], idx);                  // v_readlane, no LDS
            rr[j] = fmaf(-l, uj, rr[j]);
        }
    }
    float lg = logf(fabsf(pv_mine));
    #pragma unroll
    for (int off = 32; off; off >>= 1) lg += __shfl_down(lg, off);
    if (lane == 0) parts[w] = lg;
    __syncthreads();
    if (t == 0) out[0] = parts[0] + parts[1];
}

// ---------------------------------------------------------------------------
extern "C" void kernel_launch(void* const* d_in, const int* in_sizes, int n_in,
                              void* d_out, int out_size, void* d_ws, size_t ws_size,
                              hipStream_t stream)
{
    const float* r    = (const float*)d_in[0];
    const float* apos = (const float*)d_in[1];
    const float* V0w  = (const float*)d_in[2];
    const float* V0b  = (const float*)d_in[3];
    const float* W0w  = (const float*)d_in[4];
    const float* W0b  = (const float*)d_in[5];
    const float* V1w  = (const float*)d_in[6];
    const float* V1b  = (const float*)d_in[7];
    const float* W1w  = (const float*)d_in[8];
    const float* W1b  = (const float*)d_in[9];
    const float* V2w  = (const float*)d_in[10];
    const float* V2b  = (const float*)d_in[11];
    const float* W2w  = (const float*)d_in[12];
    const float* W2b  = (const float*)d_in[13];
    const float* afw  = (const float*)d_in[14];
    const float* afb  = (const float*)d_in[15];
    const float* vhuw = (const float*)d_in[16];
    const float* vhub = (const float*)d_in[17];
    const float* vhdw = (const float*)d_in[18];
    const float* vhdb = (const float*)d_in[19];
    const float* wuw  = (const float*)d_in[20];
    const float* wub  = (const float*)d_in[21];
    const float* wdw  = (const float*)d_in[22];
    const float* wdb  = (const float*)d_in[23];

    float* ws    = (float*)d_ws;
    float* sv0   = ws;                    // 128*128
    float* p0    = sv0  + 128*128;        // 128*128*4
    float* pA    = p0   + 128*128*4;      // 128*128*64
    float* pB    = pA   + 128*128*64;     // 128*128*64
    float* svA   = pB   + 128*128*64;     // 128*512
    float* svB   = svA  + 128*512;        // 128*512
    float* expv  = svB  + 128*512;        // 128
    float* t1g   = expv + 128;            // 512
    float* pme   = t1g  + 512;            // 128*128
    float* orb   = pme  + 128*128;        // 2*64*64

    geom_kernel<<<128, 128, 0, stream>>>(r, apos, sv0, p0, expv);

    // layer 0: grid = PB(2) + t1(8) + B(512) = 522
    mb_kernel<128, 4, false><<<522, 256, 0, stream>>>(sv0, p0, W0w, W0b, V0w, V0b, pme, t1g, pA);
    a_kernel<128, 4><<<256, 512, 0, stream>>>(sv0, pme, t1g, V0w, svA);

    // layer 1: grid = 32 + 8 + 512 = 552
    mb_kernel<512, 64, true><<<552, 256, 0, stream>>>(svA, pA, W1w, W1b, V1w, V1b, pme, t1g, pB);
    a_kernel<512, 64><<<256, 512, 0, stream>>>(svA, pme, t1g, V1w, svB);

    // layer 2
    mb_kernel<512, 64, true><<<552, 256, 0, stream>>>(svB, pB, W2w, W2b, V2w, V2b, pme, t1g, pA);
    a_kernel<512, 64><<<256, 512, 0, stream>>>(svB, pme, t1g, V2w, svA);

    // after-layer: means + t1 only (grid = 32 + 8 = 40)
    mb_kernel<512, 64, true><<<40, 256, 0, stream>>>(svA, pA, W2w, W2b, afw, afb, pme, t1g, pB);
    a_kernel<512, 64><<<256, 512, 0, stream>>>(svA, pme, t1g, afw, svB);

    headsw_kernel<<<128, 512, 0, stream>>>(svB, vhuw, vhub, vhdw, vhdb,
                                           wuw, wub, wdw, wdb, expv, orb);
    det_kernel<<<1, 128, 0, stream>>>(orb, (float*)d_out);
}